// Round 1
// baseline (453.958 us; speedup 1.0000x reference)
//
#include <hip/hip_runtime.h>
#include <math.h>

#define DHID 128
#define NCLS 40

// ---------------- GEMM: H = X @ W  (X:[n,128], W:[128,128]) ----------------
// block 256 = 8 rows x 32 col-groups(4 cols each). W streamed from L2 as float4.
__global__ __launch_bounds__(256) void gemm128_kernel(
    const float* __restrict__ X, const float* __restrict__ W,
    float* __restrict__ H, int n) {
  int t = threadIdx.x;
  int r = t >> 5;
  int c0 = (t & 31) << 2;
  int row = blockIdx.x * 8 + r;
  if (row >= n) return;
  const float* xrow = X + (size_t)row * DHID;
  float a0 = 0.f, a1 = 0.f, a2 = 0.f, a3 = 0.f;
#pragma unroll 8
  for (int k = 0; k < DHID; ++k) {
    float xv = xrow[k];
    float4 wv = *reinterpret_cast<const float4*>(W + k * DHID + c0);
    a0 = fmaf(xv, wv.x, a0);
    a1 = fmaf(xv, wv.y, a1);
    a2 = fmaf(xv, wv.z, a2);
    a3 = fmaf(xv, wv.w, a3);
  }
  *reinterpret_cast<float4*>(H + (size_t)row * DHID + c0) =
      make_float4(a0, a1, a2, a3);
}

// ---------------- per-node attention projections el = h.aW[:128], er = h.aW[128:] ----
// one wave (64 lanes) per node
__global__ __launch_bounds__(256) void elr_kernel(
    const float* __restrict__ H, const float* __restrict__ aW,
    float* __restrict__ el, float* __restrict__ er, int n) {
  int gid = blockIdx.x * blockDim.x + threadIdx.x;
  int node = gid >> 6;
  int lane = threadIdx.x & 63;
  if (node >= n) return;
  const float* h = H + (size_t)node * DHID;
  float h0 = h[lane], h1 = h[lane + 64];
  float p0 = h0 * aW[lane] + h1 * aW[lane + 64];
  float p1 = h0 * aW[128 + lane] + h1 * aW[192 + lane];
#pragma unroll
  for (int off = 32; off; off >>= 1) {
    p0 += __shfl_xor(p0, off);
    p1 += __shfl_xor(p1, off);
  }
  if (lane == 0) { el[node] = p0; er[node] = p1; }
}

// ---------------- edge pass A: e, e_sum[dst], s_sum[src], counts[dst] -------
__global__ __launch_bounds__(256) void edge_passA_kernel(
    const int* __restrict__ ei, const float* __restrict__ norm,
    const float* __restrict__ el, const float* __restrict__ er,
    const float* __restrict__ ab,
    float* __restrict__ e_arr, float* __restrict__ esum,
    float* __restrict__ ssum, int* __restrict__ counts, int E, int EP) {
  int k = blockIdx.x * blockDim.x + threadIdx.x;
  if (k >= EP) return;
  int src, dst;
  if (k < E) { src = ei[k]; dst = ei[E + k]; }
  else       { src = dst = k - E; }
  float logit = el[src] + er[dst] + ab[0];
  float lr = logit > 0.f ? logit : 0.2f * logit;
  float e = expf(lr);
  e_arr[k] = e;
  atomicAdd(&esum[dst], e);
  atomicAdd(&ssum[src], expf(norm[k]));
  atomicAdd(&counts[dst], 1);
}

// ---------------- exclusive scan of counts -> rowptr (and copy to next) -----
// single block, 1024 threads, each owns ceil(n/1024) elements
__global__ __launch_bounds__(1024) void scan_kernel(
    const int* __restrict__ counts, int* __restrict__ rowptr,
    int* __restrict__ next, int n) {
  __shared__ int sums[1024];
  int t = threadIdx.x;
  int per = (n + 1023) >> 10;
  int beg = t * per;
  int end = beg + per; if (end > n) end = n; if (beg > n) beg = n;
  int s = 0;
  for (int i = beg; i < end; ++i) s += counts[i];
  sums[t] = s;
  __syncthreads();
  for (int off = 1; off < 1024; off <<= 1) {
    int v = (t >= off) ? sums[t - off] : 0;
    __syncthreads();
    sums[t] += v;
    __syncthreads();
  }
  int run = (t == 0) ? 0 : sums[t - 1];
  for (int i = beg; i < end; ++i) {
    rowptr[i] = run; next[i] = run; run += counts[i];
  }
  if (t == 1023) rowptr[n] = sums[1023];
}

// ---------------- edge pass C: blended weight + CSR scatter -----------------
__global__ __launch_bounds__(256) void edge_passC_kernel(
    const int* __restrict__ ei, const float* __restrict__ norm,
    const float* __restrict__ e_arr, const float* __restrict__ esum,
    const float* __restrict__ ssum, const float* __restrict__ alpha,
    int* __restrict__ next, int* __restrict__ srcs, float* __restrict__ wv,
    int E, int EP) {
  int k = blockIdx.x * blockDim.x + threadIdx.x;
  if (k >= EP) return;
  int src, dst;
  if (k < E) { src = ei[k]; dst = ei[E + k]; }
  else       { src = dst = k - E; }
  float al = alpha[0];
  al = fminf(fmaxf(al, 1e-4f), 0.9999f);
  float a = e_arr[k] / esum[dst];
  float sw = expf(norm[k]) / ssum[dst];
  float w = al * a + (1.f - al) * sw;
  int pos = atomicAdd(&next[dst], 1);
  srcs[pos] = src;
  wv[pos] = w;
}

// ---------------- max-aggregation: Y[i] = relu(max_e wv*H[src] + bias) ------
// 256 threads = 2 nodes x 128 features
__global__ __launch_bounds__(256) void agg_kernel(
    const float* __restrict__ H, const int* __restrict__ rowptr,
    const int* __restrict__ srcs, const float* __restrict__ wv,
    const float* __restrict__ bias, float* __restrict__ Y, int n) {
  int node = blockIdx.x * 2 + (threadIdx.x >> 7);
  int f = threadIdx.x & 127;
  if (node >= n) return;
  int beg = rowptr[node], end = rowptr[node + 1];
  float acc = -INFINITY;
  for (int s = beg; s < end; ++s) {
    int sc = srcs[s];
    float w = wv[s];
    acc = fmaxf(acc, w * H[(size_t)sc * DHID + f]);
  }
  float o = acc + bias[f];
  Y[(size_t)node * DHID + f] = fmaxf(o, 0.f);
}

// ---------------- head: out = log_softmax(H @ Wout + bout) ------------------
// one wave per node; Wout staged in LDS
__global__ __launch_bounds__(256) void head_kernel(
    const float* __restrict__ H, const float* __restrict__ Wout,
    const float* __restrict__ bout, float* __restrict__ out, int n) {
  __shared__ float Wl[DHID * NCLS];  // 20 KB
  __shared__ float hl[4][DHID];      // 2 KB
  int t = threadIdx.x;
  for (int i = t; i < DHID * NCLS; i += 256) Wl[i] = Wout[i];
  int w = t >> 6, lane = t & 63;
  int node = blockIdx.x * 4 + w;
  if (node < n) {
    const float* hrow = H + (size_t)node * DHID;
    hl[w][lane] = hrow[lane];
    hl[w][lane + 64] = hrow[lane + 64];
  }
  __syncthreads();
  if (node >= n) return;
  float z = -INFINITY;
  if (lane < NCLS) {
    z = bout[lane];
#pragma unroll 8
    for (int k = 0; k < DHID; ++k) z = fmaf(hl[w][k], Wl[k * NCLS + lane], z);
  }
  float m = z;
#pragma unroll
  for (int off = 32; off; off >>= 1) m = fmaxf(m, __shfl_xor(m, off));
  float p = (lane < NCLS) ? expf(z - m) : 0.f;
#pragma unroll
  for (int off = 32; off; off >>= 1) p += __shfl_xor(p, off);
  float ls = logf(p);
  if (lane < NCLS) out[(size_t)node * NCLS + lane] = z - m - ls;
}

// ---------------------------------------------------------------------------
extern "C" void kernel_launch(void* const* d_in, const int* in_sizes, int n_in,
                              void* d_out, int out_size, void* d_ws, size_t ws_size,
                              hipStream_t stream) {
  const float* x     = (const float*)d_in[0];
  const int*   ei    = (const int*)d_in[1];
  const float* norm  = (const float*)d_in[2];
  const float* W1    = (const float*)d_in[3];
  const float* aW1   = (const float*)d_in[4];
  const float* ab1   = (const float*)d_in[5];
  const float* alpha1= (const float*)d_in[6];
  const float* b1    = (const float*)d_in[7];
  const float* W2    = (const float*)d_in[8];
  const float* aW2   = (const float*)d_in[9];
  const float* ab2   = (const float*)d_in[10];
  const float* alpha2= (const float*)d_in[11];
  const float* b2    = (const float*)d_in[12];
  const float* Wout  = (const float*)d_in[13];
  const float* bout  = (const float*)d_in[14];
  float* out = (float*)d_out;

  const int N  = in_sizes[0] / DHID;
  const int E  = in_sizes[1] / 2;
  const int EP = E + N;

  // workspace carve-up (256B aligned)
  char* ws = (char*)d_ws;
  size_t off = 0;
  auto alloc = [&](size_t bytes) -> void* {
    void* p = ws + off;
    off += (bytes + 255) & ~(size_t)255;
    return p;
  };
  float* A     = (float*)alloc((size_t)N * DHID * 4);  // pre-attn h
  float* B     = (float*)alloc((size_t)N * DHID * 4);  // activated output
  float* el    = (float*)alloc((size_t)N * 4);
  float* er    = (float*)alloc((size_t)N * 4);
  float* esum  = (float*)alloc((size_t)N * 4);
  float* ssum  = (float*)alloc((size_t)N * 4);
  int*   counts= (int*)  alloc((size_t)N * 4);
  int*   rowptr= (int*)  alloc((size_t)(N + 1) * 4);
  int*   nxt   = (int*)  alloc((size_t)N * 4);
  float* e_arr = (float*)alloc((size_t)EP * 4);
  int*   srcs  = (int*)  alloc((size_t)EP * 4);
  float* wvv   = (float*)alloc((size_t)EP * 4);

  const int gGemm  = (N + 7) / 8;
  const int gElr   = (N + 3) / 4;      // 4 waves/block, 1 node/wave
  const int gEdge  = (EP + 255) / 256;
  const int gAgg   = (N + 1) / 2;
  const int gHead  = (N + 3) / 4;

  struct Layer {
    const float *Xin, *W, *aW, *ab, *alpha, *bias;
    float* Yout;
  } layers[2] = {
    { x, W1, aW1, ab1, alpha1, b1, B },
    { B, W2, aW2, ab2, alpha2, b2, B },
  };

  for (int L = 0; L < 2; ++L) {
    hipMemsetAsync(esum,   0, (size_t)N * 4, stream);
    hipMemsetAsync(ssum,   0, (size_t)N * 4, stream);
    hipMemsetAsync(counts, 0, (size_t)N * 4, stream);
    gemm128_kernel<<<gGemm, 256, 0, stream>>>(layers[L].Xin, layers[L].W, A, N);
    elr_kernel<<<gElr, 256, 0, stream>>>(A, layers[L].aW, el, er, N);
    edge_passA_kernel<<<gEdge, 256, 0, stream>>>(ei, norm, el, er, layers[L].ab,
                                                 e_arr, esum, ssum, counts, E, EP);
    scan_kernel<<<1, 1024, 0, stream>>>(counts, rowptr, nxt, N);
    edge_passC_kernel<<<gEdge, 256, 0, stream>>>(ei, norm, e_arr, esum, ssum,
                                                 layers[L].alpha, nxt, srcs, wvv,
                                                 E, EP);
    agg_kernel<<<gAgg, 256, 0, stream>>>(A, rowptr, srcs, wvv, layers[L].bias,
                                         layers[L].Yout, N);
  }

  head_kernel<<<gHead, 256, 0, stream>>>(B, Wout, bout, out, N);
}

// Round 2
// 219.110 us; speedup vs baseline: 2.0718x; 2.0718x over previous
//
#include <hip/hip_runtime.h>
#include <math.h>

#define DHID 128
#define NCLS 40

// ============ fused GEMM + attention projections =============================
// H = X @ W  (X:[n,128], W:[128,128]);  el = H @ aW[:128];  er = H @ aW[128:]
// 256 threads, 32 rows/block. Thread = 4 rows (rg=t>>5, j=0..3) x 4 cols
// (c0=(t&31)*4). W staged in LDS k-tiled (2 x 32KB), X tile 16KB (reused for
// the elr partial-reduce). 48KB LDS -> 3 blocks/CU.
__global__ __launch_bounds__(256) void gemm_elr_kernel(
    const float* __restrict__ X, const float* __restrict__ W,
    const float* __restrict__ aW, float* __restrict__ H,
    float* __restrict__ el, float* __restrict__ er, int n) {
  __shared__ float Ws[64 * 128];    // 32 KB (one k-half of W)
  __shared__ float Xs[32 * 128];    // 16 KB; reused as partial buf after loop
  int t = threadIdx.x;
  int rg = t >> 5;                  // 0..7
  int c0 = (t & 31) << 2;           // 0..124
  int rowBase = blockIdx.x * 32;

  // stage X tile [32][128]
#pragma unroll
  for (int q = 0; q < 4; ++q) {
    int i4 = t + q * 256;           // float4 index, 1024 total
    int r = i4 >> 5, c = (i4 & 31) << 2;
    int gr = rowBase + r;
    float4 v = (gr < n)
        ? *reinterpret_cast<const float4*>(X + (size_t)gr * DHID + c)
        : make_float4(0.f, 0.f, 0.f, 0.f);
    *reinterpret_cast<float4*>(Xs + r * DHID + c) = v;
  }

  float acc[4][4];
#pragma unroll
  for (int j = 0; j < 4; ++j)
#pragma unroll
    for (int c = 0; c < 4; ++c) acc[j][c] = 0.f;

  for (int kt = 0; kt < 2; ++kt) {
    __syncthreads();
    const float* Wsrc = W + kt * 64 * DHID;
#pragma unroll
    for (int q = 0; q < 8; ++q) {   // stage 32KB W half
      int i4 = t + q * 256;
      *reinterpret_cast<float4*>(Ws + i4 * 4) =
          *reinterpret_cast<const float4*>(Wsrc + i4 * 4);
    }
    __syncthreads();
#pragma unroll 2
    for (int k = 0; k < 64; k += 4) {
      float4 xv[4];
#pragma unroll
      for (int j = 0; j < 4; ++j)
        xv[j] = *reinterpret_cast<const float4*>(
            Xs + (rg * 4 + j) * DHID + kt * 64 + k);
#pragma unroll
      for (int kk = 0; kk < 4; ++kk) {
        float4 wv = *reinterpret_cast<const float4*>(Ws + (k + kk) * DHID + c0);
#pragma unroll
        for (int j = 0; j < 4; ++j) {
          float xj = (&xv[j].x)[kk];
          acc[j][0] = fmaf(xj, wv.x, acc[j][0]);
          acc[j][1] = fmaf(xj, wv.y, acc[j][1]);
          acc[j][2] = fmaf(xj, wv.z, acc[j][2]);
          acc[j][3] = fmaf(xj, wv.w, acc[j][3]);
        }
      }
    }
  }

  // write H
#pragma unroll
  for (int j = 0; j < 4; ++j) {
    int gr = rowBase + rg * 4 + j;
    if (gr < n)
      *reinterpret_cast<float4*>(H + (size_t)gr * DHID + c0) =
          make_float4(acc[j][0], acc[j][1], acc[j][2], acc[j][3]);
  }

  // elr partials: pl[j] = acc[j] . aW[c0..c0+3], pr with aW[128+...]
  float4 al4 = *reinterpret_cast<const float4*>(aW + c0);
  float4 ar4 = *reinterpret_cast<const float4*>(aW + DHID + c0);
  __syncthreads();                  // all Xs reads done; safe to reuse
  float* P = Xs;                    // P[2][32][33] = 8448 B
#pragma unroll
  for (int j = 0; j < 4; ++j) {
    int r = rg * 4 + j;
    float pl = acc[j][0] * al4.x + acc[j][1] * al4.y +
               acc[j][2] * al4.z + acc[j][3] * al4.w;
    float pr = acc[j][0] * ar4.x + acc[j][1] * ar4.y +
               acc[j][2] * ar4.z + acc[j][3] * ar4.w;
    P[r * 33 + (t & 31)] = pl;
    P[1056 + r * 33 + (t & 31)] = pr;
  }
  __syncthreads();
  if (t < 64) {
    int half = t >> 5, r = t & 31;
    const float* Pr = P + half * 1056 + r * 33;
    float s = 0.f;
#pragma unroll
    for (int c = 0; c < 32; ++c) s += Pr[c];
    int gr = rowBase + r;
    if (gr < n) { if (half) er[gr] = s; else el[gr] = s; }
  }
}

// ============ CSR build (graph-static, once per call) ========================
__global__ __launch_bounds__(256) void build_count_kernel(
    const int* __restrict__ ei, const float* __restrict__ norm,
    int* __restrict__ counts, float* __restrict__ ssum, int E, int EP) {
  int k = blockIdx.x * blockDim.x + threadIdx.x;
  if (k >= EP) return;
  int src, dst;
  if (k < E) { src = ei[k]; dst = ei[E + k]; }
  else       { src = dst = k - E; }
  atomicAdd(&counts[dst], 1);
  atomicAdd(&ssum[src], expf(norm[k]));
}

// single block, 1024 threads: exclusive scan counts -> rowptr (+copy to nxt)
__global__ __launch_bounds__(1024) void scan_kernel(
    const int* __restrict__ counts, int* __restrict__ rowptr,
    int* __restrict__ nxt, int n) {
  __shared__ int sums[1024];
  int t = threadIdx.x;
  int per = (n + 1023) >> 10;
  int beg = t * per;
  int end = beg + per; if (end > n) end = n; if (beg > n) beg = n;
  int s = 0;
  for (int i = beg; i < end; ++i) s += counts[i];
  sums[t] = s;
  __syncthreads();
  for (int off = 1; off < 1024; off <<= 1) {
    int v = (t >= off) ? sums[t - off] : 0;
    __syncthreads();
    sums[t] += v;
    __syncthreads();
  }
  int run = (t == 0) ? 0 : sums[t - 1];
  for (int i = beg; i < end; ++i) {
    rowptr[i] = run; nxt[i] = run; run += counts[i];
  }
  if (t == 1023) rowptr[n] = sums[1023];
}

// scatter: slot srcs + layer-independent similarity weight sw (scattered)
__global__ __launch_bounds__(256) void build_scatter_kernel(
    const int* __restrict__ ei, const float* __restrict__ norm,
    const float* __restrict__ ssum, int* __restrict__ nxt,
    int* __restrict__ srcs, float* __restrict__ swp, int E, int EP) {
  int k = blockIdx.x * blockDim.x + threadIdx.x;
  if (k >= EP) return;
  int src, dst;
  if (k < E) { src = ei[k]; dst = ei[E + k]; }
  else       { src = dst = k - E; }
  int pos = atomicAdd(&nxt[dst], 1);
  srcs[pos] = src;
  swp[pos] = expf(norm[k]) / ssum[dst];
}

// ============ aggregation: Y = relu(segment_max(w * H[src]) + bias) ==========
// one wave per node. Pass 1: softmax denom (lane-parallel + shuffle reduce).
// Pass 2: serial over edges, 64 lanes x float2 features, inline e & blend.
__global__ __launch_bounds__(256) void agg_kernel(
    const float* __restrict__ H, const int* __restrict__ rowptr,
    const int* __restrict__ srcs, const float* __restrict__ swp,
    const float* __restrict__ el, const float* __restrict__ er,
    const float* __restrict__ ab, const float* __restrict__ alpha,
    const float* __restrict__ bias, float* __restrict__ Y, int n) {
  int node = blockIdx.x * 4 + (threadIdx.x >> 6);
  int lane = threadIdx.x & 63;
  if (node >= n) return;
  int beg = rowptr[node], end = rowptr[node + 1];
  float base = er[node] + ab[0];
  float al = alpha[0];
  al = fminf(fmaxf(al, 1e-4f), 0.9999f);
  float oma = 1.f - al;

  // pass 1: e_sum
  float es = 0.f;
  for (int s = beg + lane; s < end; s += 64) {
    float g = el[srcs[s]] + base;
    es += expf(g > 0.f ? g : 0.2f * g);
  }
#pragma unroll
  for (int off = 32; off; off >>= 1) es += __shfl_xor(es, off);
  float invEs = al / es;            // fold alpha into the reciprocal

  // pass 2: blended-weight max over edges
  float2 acc = make_float2(-INFINITY, -INFINITY);
  int s = beg;
  for (; s + 1 < end; s += 2) {
    int sc0 = srcs[s], sc1 = srcs[s + 1];
    float sw0 = swp[s], sw1 = swp[s + 1];
    float l0 = el[sc0] + base, l1 = el[sc1] + base;
    float2 h0 = *reinterpret_cast<const float2*>(H + sc0 * DHID + lane * 2);
    float2 h1 = *reinterpret_cast<const float2*>(H + sc1 * DHID + lane * 2);
    float e0 = expf(l0 > 0.f ? l0 : 0.2f * l0);
    float e1 = expf(l1 > 0.f ? l1 : 0.2f * l1);
    float w0 = e0 * invEs + oma * sw0;
    float w1 = e1 * invEs + oma * sw1;
    acc.x = fmaxf(acc.x, fmaxf(w0 * h0.x, w1 * h1.x));
    acc.y = fmaxf(acc.y, fmaxf(w0 * h0.y, w1 * h1.y));
  }
  if (s < end) {
    int sc = srcs[s];
    float sw = swp[s];
    float l = el[sc] + base;
    float2 h = *reinterpret_cast<const float2*>(H + sc * DHID + lane * 2);
    float e = expf(l > 0.f ? l : 0.2f * l);
    float w = e * invEs + oma * sw;
    acc.x = fmaxf(acc.x, w * h.x);
    acc.y = fmaxf(acc.y, w * h.y);
  }
  float2 b = *reinterpret_cast<const float2*>(bias + lane * 2);
  float2 o;
  o.x = fmaxf(acc.x + b.x, 0.f);
  o.y = fmaxf(acc.y + b.y, 0.f);
  *reinterpret_cast<float2*>(Y + (size_t)node * DHID + lane * 2) = o;
}

// ============ head: out = log_softmax(H @ Wout + bout) =======================
__global__ __launch_bounds__(256) void head_kernel(
    const float* __restrict__ H, const float* __restrict__ Wout,
    const float* __restrict__ bout, float* __restrict__ out, int n) {
  __shared__ float Wl[DHID * NCLS];  // 20 KB
  __shared__ float hl[4][DHID];
  int t = threadIdx.x;
  for (int i = t; i < DHID * NCLS; i += 256) Wl[i] = Wout[i];
  int w = t >> 6, lane = t & 63;
  int node = blockIdx.x * 4 + w;
  if (node < n) {
    const float* hrow = H + (size_t)node * DHID;
    hl[w][lane] = hrow[lane];
    hl[w][lane + 64] = hrow[lane + 64];
  }
  __syncthreads();
  if (node >= n) return;
  float z = -INFINITY;
  if (lane < NCLS) {
    z = bout[lane];
#pragma unroll 8
    for (int k = 0; k < DHID; ++k) z = fmaf(hl[w][k], Wl[k * NCLS + lane], z);
  }
  float m = z;
#pragma unroll
  for (int off = 32; off; off >>= 1) m = fmaxf(m, __shfl_xor(m, off));
  float p = (lane < NCLS) ? expf(z - m) : 0.f;
#pragma unroll
  for (int off = 32; off; off >>= 1) p += __shfl_xor(p, off);
  float ls = logf(p);
  if (lane < NCLS) out[(size_t)node * NCLS + lane] = z - m - ls;
}

// ===========================================================================
extern "C" void kernel_launch(void* const* d_in, const int* in_sizes, int n_in,
                              void* d_out, int out_size, void* d_ws, size_t ws_size,
                              hipStream_t stream) {
  const float* x     = (const float*)d_in[0];
  const int*   ei    = (const int*)d_in[1];
  const float* norm  = (const float*)d_in[2];
  const float* W1    = (const float*)d_in[3];
  const float* aW1   = (const float*)d_in[4];
  const float* ab1   = (const float*)d_in[5];
  const float* alpha1= (const float*)d_in[6];
  const float* b1    = (const float*)d_in[7];
  const float* W2    = (const float*)d_in[8];
  const float* aW2   = (const float*)d_in[9];
  const float* ab2   = (const float*)d_in[10];
  const float* alpha2= (const float*)d_in[11];
  const float* b2    = (const float*)d_in[12];
  const float* Wout  = (const float*)d_in[13];
  const float* bout  = (const float*)d_in[14];
  float* out = (float*)d_out;

  const int N  = in_sizes[0] / DHID;
  const int E  = in_sizes[1] / 2;
  const int EP = E + N;

  char* ws = (char*)d_ws;
  size_t off = 0;
  auto alloc = [&](size_t bytes) -> void* {
    void* p = ws + off;
    off += (bytes + 255) & ~(size_t)255;
    return p;
  };
  const size_t padN4 = ((size_t)N * 4 + 255) & ~(size_t)255;
  int*   counts = (int*)  alloc((size_t)N * 4);       // \ contiguous: one memset
  float* ssum   = (float*)alloc((size_t)N * 4);       // /
  float* A      = (float*)alloc((size_t)N * DHID * 4);  // pre-attn h
  float* B      = (float*)alloc((size_t)N * DHID * 4);  // activated output
  float* el     = (float*)alloc((size_t)N * 4);
  float* er     = (float*)alloc((size_t)N * 4);
  int*   rowptr = (int*)  alloc((size_t)(N + 1) * 4);
  int*   nxt    = (int*)  alloc((size_t)N * 4);
  int*   srcs   = (int*)  alloc((size_t)EP * 4);
  float* swp    = (float*)alloc((size_t)EP * 4);

  const int gGemm = (N + 31) / 32;
  const int gEdge = (EP + 255) / 256;
  const int gAgg  = (N + 3) / 4;
  const int gHead = (N + 3) / 4;

  // ---- graph-static build (shared by both layers) ----
  hipMemsetAsync(counts, 0, 2 * padN4, stream);   // counts + ssum
  build_count_kernel<<<gEdge, 256, 0, stream>>>(ei, norm, counts, ssum, E, EP);
  scan_kernel<<<1, 1024, 0, stream>>>(counts, rowptr, nxt, N);
  build_scatter_kernel<<<gEdge, 256, 0, stream>>>(ei, norm, ssum, nxt, srcs,
                                                  swp, E, EP);

  // ---- layer 1 ----
  gemm_elr_kernel<<<gGemm, 256, 0, stream>>>(x, W1, aW1, A, el, er, N);
  agg_kernel<<<gAgg, 256, 0, stream>>>(A, rowptr, srcs, swp, el, er, ab1,
                                       alpha1, b1, B, N);
  // ---- layer 2 ----
  gemm_elr_kernel<<<gGemm, 256, 0, stream>>>(B, W2, aW2, A, el, er, N);
  agg_kernel<<<gAgg, 256, 0, stream>>>(A, rowptr, srcs, swp, el, er, ab2,
                                       alpha2, b2, B, N);
  // ---- head ----
  head_kernel<<<gHead, 256, 0, stream>>>(B, Wout, bout, out, N);
}

// Round 3
// 205.570 us; speedup vs baseline: 2.2083x; 1.0659x over previous
//
#include <hip/hip_runtime.h>
#include <math.h>

#define DHID 128
#define NCLS 40

// ============ zero counts+ssum (replaces pathological rocclr fill) ==========
__global__ __launch_bounds__(256) void zero_kernel(
    int* __restrict__ counts, float* __restrict__ ssum, int n) {
  int i = blockIdx.x * 256 + threadIdx.x;
  if (i < n) { counts[i] = 0; ssum[i] = 0.f; }
}

// ============ fused GEMM + attention projections =============================
// H = X @ W;  el = H @ aW[:128];  er = H @ aW[128:]
// 256 threads, 32 rows/block, 4x4 register tile, W k-tiled 2x32KB in LDS.
__global__ __launch_bounds__(256) void gemm_elr_kernel(
    const float* __restrict__ X, const float* __restrict__ W,
    const float* __restrict__ aW, float* __restrict__ H,
    float* __restrict__ el, float* __restrict__ er, int n) {
  __shared__ float Ws[64 * 128];    // 32 KB
  __shared__ float Xs[32 * 128];    // 16 KB; reused as partial buf after loop
  int t = threadIdx.x;
  int rg = t >> 5;
  int c0 = (t & 31) << 2;
  int rowBase = blockIdx.x * 32;

#pragma unroll
  for (int q = 0; q < 4; ++q) {
    int i4 = t + q * 256;
    int r = i4 >> 5, c = (i4 & 31) << 2;
    int gr = rowBase + r;
    float4 v = (gr < n)
        ? *reinterpret_cast<const float4*>(X + (size_t)gr * DHID + c)
        : make_float4(0.f, 0.f, 0.f, 0.f);
    *reinterpret_cast<float4*>(Xs + r * DHID + c) = v;
  }

  float acc[4][4];
#pragma unroll
  for (int j = 0; j < 4; ++j)
#pragma unroll
    for (int c = 0; c < 4; ++c) acc[j][c] = 0.f;

  for (int kt = 0; kt < 2; ++kt) {
    __syncthreads();
    const float* Wsrc = W + kt * 64 * DHID;
#pragma unroll
    for (int q = 0; q < 8; ++q) {
      int i4 = t + q * 256;
      *reinterpret_cast<float4*>(Ws + i4 * 4) =
          *reinterpret_cast<const float4*>(Wsrc + i4 * 4);
    }
    __syncthreads();
#pragma unroll 2
    for (int k = 0; k < 64; k += 4) {
      float4 xv[4];
#pragma unroll
      for (int j = 0; j < 4; ++j)
        xv[j] = *reinterpret_cast<const float4*>(
            Xs + (rg * 4 + j) * DHID + kt * 64 + k);
#pragma unroll
      for (int kk = 0; kk < 4; ++kk) {
        float4 wv = *reinterpret_cast<const float4*>(Ws + (k + kk) * DHID + c0);
#pragma unroll
        for (int j = 0; j < 4; ++j) {
          float xj = (&xv[j].x)[kk];
          acc[j][0] = fmaf(xj, wv.x, acc[j][0]);
          acc[j][1] = fmaf(xj, wv.y, acc[j][1]);
          acc[j][2] = fmaf(xj, wv.z, acc[j][2]);
          acc[j][3] = fmaf(xj, wv.w, acc[j][3]);
        }
      }
    }
  }

#pragma unroll
  for (int j = 0; j < 4; ++j) {
    int gr = rowBase + rg * 4 + j;
    if (gr < n)
      *reinterpret_cast<float4*>(H + (size_t)gr * DHID + c0) =
          make_float4(acc[j][0], acc[j][1], acc[j][2], acc[j][3]);
  }

  float4 al4 = *reinterpret_cast<const float4*>(aW + c0);
  float4 ar4 = *reinterpret_cast<const float4*>(aW + DHID + c0);
  __syncthreads();
  float* P = Xs;                    // P[2][32][33]
#pragma unroll
  for (int j = 0; j < 4; ++j) {
    int r = rg * 4 + j;
    float pl = acc[j][0] * al4.x + acc[j][1] * al4.y +
               acc[j][2] * al4.z + acc[j][3] * al4.w;
    float pr = acc[j][0] * ar4.x + acc[j][1] * ar4.y +
               acc[j][2] * ar4.z + acc[j][3] * ar4.w;
    P[r * 33 + (t & 31)] = pl;
    P[1056 + r * 33 + (t & 31)] = pr;
  }
  __syncthreads();
  if (t < 64) {
    int half = t >> 5, r = t & 31;
    const float* Pr = P + half * 1056 + r * 33;
    float s = 0.f;
#pragma unroll
    for (int c = 0; c < 32; ++c) s += Pr[c];
    int gr = rowBase + r;
    if (gr < n) { if (half) er[gr] = s; else el[gr] = s; }
  }
}

// ============ CSR build (graph-static, once per call) ========================
__global__ __launch_bounds__(256) void build_count_kernel(
    const int* __restrict__ ei, const float* __restrict__ norm,
    int* __restrict__ counts, float* __restrict__ ssum, int E, int EP) {
  int k = blockIdx.x * blockDim.x + threadIdx.x;
  if (k >= EP) return;
  int src, dst;
  if (k < E) { src = ei[k]; dst = ei[E + k]; }
  else       { src = dst = k - E; }
  atomicAdd(&counts[dst], 1);
  atomicAdd(&ssum[src], expf(norm[k]));
}

__global__ __launch_bounds__(1024) void scan_kernel(
    const int* __restrict__ counts, int* __restrict__ rowptr,
    int* __restrict__ nxt, int n) {
  __shared__ int sums[1024];
  int t = threadIdx.x;
  int per = (n + 1023) >> 10;
  int beg = t * per;
  int end = beg + per; if (end > n) end = n; if (beg > n) beg = n;
  int s = 0;
  for (int i = beg; i < end; ++i) s += counts[i];
  sums[t] = s;
  __syncthreads();
  for (int off = 1; off < 1024; off <<= 1) {
    int v = (t >= off) ? sums[t - off] : 0;
    __syncthreads();
    sums[t] += v;
    __syncthreads();
  }
  int run = (t == 0) ? 0 : sums[t - 1];
  for (int i = beg; i < end; ++i) {
    rowptr[i] = run; nxt[i] = run; run += counts[i];
  }
  if (t == 1023) rowptr[n] = sums[1023];
}

__global__ __launch_bounds__(256) void build_scatter_kernel(
    const int* __restrict__ ei, const float* __restrict__ norm,
    const float* __restrict__ ssum, int* __restrict__ nxt,
    int* __restrict__ srcs, float* __restrict__ swp, int E, int EP) {
  int k = blockIdx.x * blockDim.x + threadIdx.x;
  if (k >= EP) return;
  int src, dst;
  if (k < E) { src = ei[k]; dst = ei[E + k]; }
  else       { src = dst = k - E; }
  int pos = atomicAdd(&nxt[dst], 1);
  srcs[pos] = src;
  swp[pos] = expf(norm[k]) / ssum[dst];
}

// ============ aggregation: Y = relu(segment_max(w * H[src]) + bias) ==========
// one wave per node. Pass 1: softmax denom, 64-lane parallel.
// Pass 2: half-wave per edge (even/odd CSR slots), float4 per lane,
//         2 independent edges in flight per half -> 4 edges/wave-iter.
__global__ __launch_bounds__(256) void agg_kernel(
    const float* __restrict__ H, const int* __restrict__ rowptr,
    const int* __restrict__ srcs, const float* __restrict__ swp,
    const float* __restrict__ el, const float* __restrict__ er,
    const float* __restrict__ ab, const float* __restrict__ alpha,
    const float* __restrict__ bias, float* __restrict__ Y, int n) {
  int node = blockIdx.x * 4 + (threadIdx.x >> 6);
  int lane = threadIdx.x & 63;
  if (node >= n) return;
  int beg = rowptr[node], end = rowptr[node + 1];
  float base = er[node] + ab[0];
  float al = fminf(fmaxf(alpha[0], 1e-4f), 0.9999f);
  float oma = 1.f - al;

  // pass 1: e_sum
  float es = 0.f;
  for (int s = beg + lane; s < end; s += 64) {
    float g = el[srcs[s]] + base;
    es += expf(g > 0.f ? g : 0.2f * g);
  }
#pragma unroll
  for (int off = 32; off; off >>= 1) es += __shfl_xor(es, off);
  float invEs = al / es;

  // pass 2
  int half = lane >> 5;
  int fl = (lane & 31) << 2;
  float4 acc = make_float4(-INFINITY, -INFINITY, -INFINITY, -INFINITY);
  int s = beg + half;
  for (; s + 2 < end; s += 4) {
    int sc0 = srcs[s], sc1 = srcs[s + 2];
    float sw0 = swp[s], sw1 = swp[s + 2];
    float l0 = el[sc0] + base, l1 = el[sc1] + base;
    float4 h0 = *reinterpret_cast<const float4*>(H + (size_t)sc0 * DHID + fl);
    float4 h1 = *reinterpret_cast<const float4*>(H + (size_t)sc1 * DHID + fl);
    float w0 = expf(l0 > 0.f ? l0 : 0.2f * l0) * invEs + oma * sw0;
    float w1 = expf(l1 > 0.f ? l1 : 0.2f * l1) * invEs + oma * sw1;
    acc.x = fmaxf(acc.x, fmaxf(w0 * h0.x, w1 * h1.x));
    acc.y = fmaxf(acc.y, fmaxf(w0 * h0.y, w1 * h1.y));
    acc.z = fmaxf(acc.z, fmaxf(w0 * h0.z, w1 * h1.z));
    acc.w = fmaxf(acc.w, fmaxf(w0 * h0.w, w1 * h1.w));
  }
  if (s < end) {
    int sc = srcs[s];
    float sw = swp[s];
    float l = el[sc] + base;
    float4 h = *reinterpret_cast<const float4*>(H + (size_t)sc * DHID + fl);
    float w = expf(l > 0.f ? l : 0.2f * l) * invEs + oma * sw;
    acc.x = fmaxf(acc.x, w * h.x);
    acc.y = fmaxf(acc.y, w * h.y);
    acc.z = fmaxf(acc.z, w * h.z);
    acc.w = fmaxf(acc.w, w * h.w);
  }
  // combine halves
  acc.x = fmaxf(acc.x, __shfl_xor(acc.x, 32));
  acc.y = fmaxf(acc.y, __shfl_xor(acc.y, 32));
  acc.z = fmaxf(acc.z, __shfl_xor(acc.z, 32));
  acc.w = fmaxf(acc.w, __shfl_xor(acc.w, 32));
  if (half == 0) {
    float4 b = *reinterpret_cast<const float4*>(bias + fl);
    float4 o;
    o.x = fmaxf(acc.x + b.x, 0.f);
    o.y = fmaxf(acc.y + b.y, 0.f);
    o.z = fmaxf(acc.z + b.z, 0.f);
    o.w = fmaxf(acc.w + b.w, 0.f);
    *reinterpret_cast<float4*>(Y + (size_t)node * DHID + fl) = o;
  }
}

// ============ head: out = log_softmax(H @ Wout + bout), 16 nodes/block =======
__global__ __launch_bounds__(256) void head_kernel(
    const float* __restrict__ H, const float* __restrict__ Wout,
    const float* __restrict__ bout, float* __restrict__ out, int n) {
  __shared__ float Wl[DHID * NCLS];  // 20 KB
  __shared__ float hl[4][DHID];
  int t = threadIdx.x;
  for (int i = t; i < DHID * NCLS; i += 256) Wl[i] = Wout[i];
  int w = t >> 6, lane = t & 63;
  __syncthreads();
  for (int nd = 0; nd < 4; ++nd) {
    int node = blockIdx.x * 16 + nd * 4 + w;
    if (node < n) {
      const float* hrow = H + (size_t)node * DHID;
      hl[w][lane] = hrow[lane];
      hl[w][lane + 64] = hrow[lane + 64];
    }
    __syncthreads();
    float z = -INFINITY;
    bool act = (node < n) && (lane < NCLS);
    if (act) {
      z = bout[lane];
#pragma unroll 8
      for (int k = 0; k < DHID; ++k) z = fmaf(hl[w][k], Wl[k * NCLS + lane], z);
    }
    float m = z;
#pragma unroll
    for (int off = 32; off; off >>= 1) m = fmaxf(m, __shfl_xor(m, off));
    float p = act ? expf(z - m) : 0.f;
#pragma unroll
    for (int off = 32; off; off >>= 1) p += __shfl_xor(p, off);
    float ls = logf(p);
    if (act) out[(size_t)node * NCLS + lane] = z - m - ls;
    __syncthreads();
  }
}

// ===========================================================================
extern "C" void kernel_launch(void* const* d_in, const int* in_sizes, int n_in,
                              void* d_out, int out_size, void* d_ws, size_t ws_size,
                              hipStream_t stream) {
  const float* x     = (const float*)d_in[0];
  const int*   ei    = (const int*)d_in[1];
  const float* norm  = (const float*)d_in[2];
  const float* W1    = (const float*)d_in[3];
  const float* aW1   = (const float*)d_in[4];
  const float* ab1   = (const float*)d_in[5];
  const float* alpha1= (const float*)d_in[6];
  const float* b1    = (const float*)d_in[7];
  const float* W2    = (const float*)d_in[8];
  const float* aW2   = (const float*)d_in[9];
  const float* ab2   = (const float*)d_in[10];
  const float* alpha2= (const float*)d_in[11];
  const float* b2    = (const float*)d_in[12];
  const float* Wout  = (const float*)d_in[13];
  const float* bout  = (const float*)d_in[14];
  float* out = (float*)d_out;

  const int N  = in_sizes[0] / DHID;
  const int E  = in_sizes[1] / 2;
  const int EP = E + N;

  char* ws = (char*)d_ws;
  size_t off = 0;
  auto alloc = [&](size_t bytes) -> void* {
    void* p = ws + off;
    off += (bytes + 255) & ~(size_t)255;
    return p;
  };
  int*   counts = (int*)  alloc((size_t)N * 4);
  float* ssum   = (float*)alloc((size_t)N * 4);
  float* A      = (float*)alloc((size_t)N * DHID * 4);
  float* B      = (float*)alloc((size_t)N * DHID * 4);
  float* el     = (float*)alloc((size_t)N * 4);
  float* er     = (float*)alloc((size_t)N * 4);
  int*   rowptr = (int*)  alloc((size_t)(N + 1) * 4);
  int*   nxt    = (int*)  alloc((size_t)N * 4);
  int*   srcs   = (int*)  alloc((size_t)EP * 4);
  float* swp    = (float*)alloc((size_t)EP * 4);

  const int gZero = (N + 255) / 256;
  const int gGemm = (N + 31) / 32;
  const int gEdge = (EP + 255) / 256;
  const int gAgg  = (N + 3) / 4;
  const int gHead = (N + 15) / 16;

  // ---- graph-static build (shared by both layers) ----
  zero_kernel<<<gZero, 256, 0, stream>>>(counts, ssum, N);
  build_count_kernel<<<gEdge, 256, 0, stream>>>(ei, norm, counts, ssum, E, EP);
  scan_kernel<<<1, 1024, 0, stream>>>(counts, rowptr, nxt, N);
  build_scatter_kernel<<<gEdge, 256, 0, stream>>>(ei, norm, ssum, nxt, srcs,
                                                  swp, E, EP);

  // ---- layer 1 ----
  gemm_elr_kernel<<<gGemm, 256, 0, stream>>>(x, W1, aW1, A, el, er, N);
  agg_kernel<<<gAgg, 256, 0, stream>>>(A, rowptr, srcs, swp, el, er, ab1,
                                       alpha1, b1, B, N);
  // ---- layer 2 ----
  gemm_elr_kernel<<<gGemm, 256, 0, stream>>>(B, W2, aW2, A, el, er, N);
  agg_kernel<<<gAgg, 256, 0, stream>>>(A, rowptr, srcs, swp, el, er, ab2,
                                       alpha2, b2, B, N);
  // ---- head ----
  head_kernel<<<gHead, 256, 0, stream>>>(B, Wout, bout, out, N);
}